// Round 17
// baseline (95.823 us; speedup 1.0000x reference)
//
#include <hip/hip_runtime.h>
#include <hip/hip_bf16.h>
#include <math.h>

#define S_LEN 2048
#define E_DIM 1024
#define NHEAD 8
#define DH 128
#define E3 3072

typedef short bf16x8 __attribute__((ext_vector_type(8)));
typedef short bf16x4 __attribute__((ext_vector_type(4)));
typedef float f32x4 __attribute__((ext_vector_type(4)));
typedef float f32x16 __attribute__((ext_vector_type(16)));

#define MFMA3216(a,b,c) __builtin_amdgcn_mfma_f32_32x32x16_bf16(a,b,c,0,0,0)
#define Z16 {0.f,0.f,0.f,0.f,0.f,0.f,0.f,0.f,0.f,0.f,0.f,0.f,0.f,0.f,0.f,0.f}
#define CROW(r) (((r)&3) + 8*((r)>>2))

__device__ __forceinline__ unsigned short f2bf(float f){
  union{float f; unsigned u;} x; x.f = f;
  unsigned r = x.u + 0x7FFF + ((x.u>>16)&1);
  return (unsigned short)(r>>16);
}

__device__ __forceinline__ unsigned cvtpk(float lo, float hi){
  unsigned r;
  asm("v_cvt_pk_bf16_f32 %0, %1, %2" : "=v"(r) : "v"(lo), "v"(hi));
  return r;
}

__device__ __forceinline__ float logsigf(float x){
  return fminf(x, 0.f) - log1pf(expf(-fabsf(x)));
}

typedef const __attribute__((address_space(1))) unsigned int* gas1_t;
typedef __attribute__((address_space(3))) unsigned int* las3_t;
__device__ __forceinline__ void stage16(const ushort* g, ushort* l){
  __builtin_amdgcn_global_load_lds((gas1_t)(const void*)g, (las3_t)(void*)l, 16, 0, 0);
}

// ------ Kernel A: r9's proven gates (acc[64] butterfly) + fused V^T --------
__global__ __launch_bounds__(256) void gates_qk(
    const float* __restrict__ q, const float* __restrict__ k, const float* __restrict__ v,
    const float* __restrict__ igw, const float* __restrict__ igb,
    const float* __restrict__ fgw, const float* __restrict__ fgb,
    float* __restrict__ ig_out, float* __restrict__ lsf_out,
    ushort* __restrict__ qbo, ushort* __restrict__ kbo, ushort* __restrict__ vto){
  const int t0 = blockIdx.x*4;
  const int tid = threadIdx.x;
  const int lane = tid & 63, wv = tid >> 6;
  float acc[64];
  #pragma unroll
  for (int a=0;a<64;++a) acc[a]=0.f;
  const float sc = 0.08838834764831845f;  // 1/sqrt(128)
  #pragma unroll
  for (int step=0; step<3; ++step){
    const float* src = (step==0)? q : ((step==1)? k : v);
    float4 in4[4];
    #pragma unroll
    for (int r=0;r<4;++r) in4[r] = ((const float4*)src)[(size_t)(t0+r)*256 + tid];
    if (step==0){
      #pragma unroll
      for (int r=0;r<4;++r){
        ushort4 o; o.x=f2bf(in4[r].x*sc); o.y=f2bf(in4[r].y*sc);
        o.z=f2bf(in4[r].z*sc); o.w=f2bf(in4[r].w*sc);
        ((ushort4*)qbo)[(size_t)(t0+r)*256 + tid] = o;
      }
    } else if (step==1){
      #pragma unroll
      for (int r=0;r<4;++r){
        ushort4 o; o.x=f2bf(in4[r].x); o.y=f2bf(in4[r].y);
        o.z=f2bf(in4[r].z); o.w=f2bf(in4[r].w);
        ((ushort4*)kbo)[(size_t)(t0+r)*256 + tid] = o;
      }
    } else {
      #pragma unroll
      for (int c=0;c<4;++c){
        ushort4 ov;
        ov.x = f2bf(((const float*)&in4[0])[c]);
        ov.y = f2bf(((const float*)&in4[1])[c]);
        ov.z = f2bf(((const float*)&in4[2])[c]);
        ov.w = f2bf(((const float*)&in4[3])[c]);
        *(ushort4*)(vto + (size_t)(tid*4+c)*S_LEN + t0) = ov;
      }
    }
    const int wj = step*256 + tid;
    #pragma unroll
    for (int o=0;o<8;++o){
      float4 wI = ((const float4*)igw)[o*768 + wj];
      float4 wF = ((const float4*)fgw)[o*768 + wj];
      #pragma unroll
      for (int r=0;r<4;++r){
        acc[o*4+r]    = fmaf(in4[r].x, wI.x, acc[o*4+r]);
        acc[o*4+r]    = fmaf(in4[r].y, wI.y, acc[o*4+r]);
        acc[o*4+r]    = fmaf(in4[r].z, wI.z, acc[o*4+r]);
        acc[o*4+r]    = fmaf(in4[r].w, wI.w, acc[o*4+r]);
        acc[32+o*4+r] = fmaf(in4[r].x, wF.x, acc[32+o*4+r]);
        acc[32+o*4+r] = fmaf(in4[r].y, wF.y, acc[32+o*4+r]);
        acc[32+o*4+r] = fmaf(in4[r].z, wF.z, acc[32+o*4+r]);
        acc[32+o*4+r] = fmaf(in4[r].w, wF.w, acc[32+o*4+r]);
      }
    }
  }
  int cnt = 32;
  #pragma unroll
  for (int s=0; s<6; ++s){
    const bool hib = (lane >> s) & 1;
    #pragma unroll
    for (int a=0; a<32; ++a){
      if (a < cnt){
        float sent = hib ? acc[a] : acc[a+cnt];
        float got = __shfl_xor(sent, 1<<s, 64);
        acc[a] = (hib ? acc[a+cnt] : acc[a]) + got;
      }
    }
    cnt >>= 1;
  }
  __shared__ float red[4][64];
  red[wv][lane] = acc[0];
  __syncthreads();
  if (tid < 64){
    float tot = red[0][tid]+red[1][tid]+red[2][tid]+red[3][tid];
    int a = (int)(__brev((unsigned)tid) >> 26);   // bitrev6
    int f = a >> 5, o = (a>>2)&7, r = a&3;
    int t = t0 + r;
    if (f==0) ig_out[o*S_LEN + t] = tot + igb[o];
    else      lsf_out[o*S_LEN + t] = logsigf(tot + fgb[o]);
  }
}

// ---------------- Kernel B: per-head scans ---------------------------------
__global__ __launch_bounds__(256) void scan_kernel(
    const float* __restrict__ ig, const float* __restrict__ lsf,
    float* __restrict__ cs_out, float* __restrict__ M_out, float* __restrict__ m_out){
  const int h = blockIdx.x;
  const int tid = threadIdx.x;
  __shared__ float tt[256];
  const int base = tid*8;
  const float* src = lsf + h*S_LEN;
  float loc[8]; float tot = 0.f;
  #pragma unroll
  for (int i=0;i<8;++i){ tot += src[base+i]; loc[i]=tot; }
  tt[tid]=tot; __syncthreads();
  for (int off=1; off<256; off<<=1){
    float add = (tid>=off)? tt[tid-off] : 0.f;
    __syncthreads();
    tt[tid] += add;
    __syncthreads();
  }
  const float excl = tt[tid] - tot;
  float csv[8];
  #pragma unroll
  for (int i=0;i<8;++i){ csv[i] = excl + loc[i]; cs_out[h*S_LEN+base+i]=csv[i]; }
  const float* igp = ig + h*S_LEN;
  float mloc[8], mval[8]; float mtot = -INFINITY;
  #pragma unroll
  for (int i=0;i<8;++i){
    float m = igp[base+i] - csv[i];
    mval[i] = m;
    mtot = fmaxf(mtot, m);
    mloc[i] = mtot;
  }
  __syncthreads();
  tt[tid]=mtot; __syncthreads();
  for (int off=1; off<256; off<<=1){
    float add = (tid>=off)? tt[tid-off] : -INFINITY;
    __syncthreads();
    tt[tid] = fmaxf(tt[tid], add);
    __syncthreads();
  }
  const float exclm = (tid>0)? tt[tid-1] : -INFINITY;
  #pragma unroll
  for (int i=0;i<8;++i){
    M_out[h*S_LEN+base+i] = fmaxf(exclm, mloc[i]);
    m_out[h*S_LEN+base+i] = mval[i];
  }
}

// ---- Kernel C: r15 structure, K direct global->reg (pipelined), V in LDS --
// K staged bytes were single-use in LDS -> removed (32KB/tile less staging).
// K fragments prefetched one tile ahead into static A/B register sets; the
// V-barrier's vmcnt drain covers both (wait = max, not sum).
#define LOADK9(ktv, S) {                                                     \
    const ushort* kr_ = kbh + (size_t)((ktv)*128 + sq*32 + l31)*E_DIM + hi*8; \
    ck##S##0 = *(const bf16x8*)(kr_+0);   ck##S##1 = *(const bf16x8*)(kr_+16);\
    ck##S##2 = *(const bf16x8*)(kr_+32);  ck##S##3 = *(const bf16x8*)(kr_+48);\
    ck##S##4 = *(const bf16x8*)(kr_+64);  ck##S##5 = *(const bf16x8*)(kr_+80);\
    ck##S##6 = *(const bf16x8*)(kr_+96);  ck##S##7 = *(const bf16x8*)(kr_+112); }

#define STAGE_V9(ktv) {                                                      \
    _Pragma("unroll")                                                        \
    for (int i_=0;i_<8;++i_){                                                \
      const int L_ = tid + i_*256; const int d_ = L_>>4, pc_ = L_&15;        \
      stage16(vth + (size_t)d_*S_LEN + (ktv)*128 + ((pc_^(d_&15))<<3),       \
              Vb + (size_t)L_*8); }                                          \
    if (tid < 32)                                                            \
      stage16((const ushort*)(mh + (ktv)*128) + tid*8,                       \
              (ushort*)MB + tid*8); }

#define LV9(dt, cs) (*(const bf16x8*)(Vb + (size_t)((dt)*32+l31)*128 + (((cs)^l15)<<3)))

#define COMPUTE9(S) {                                                        \
    f32x16 cc = Z16;                                                         \
    cc = MFMA3216(ck##S##0, qf0, cc);                                        \
    cc = MFMA3216(ck##S##1, qf1, cc);                                        \
    cc = MFMA3216(ck##S##2, qf2, cc);                                        \
    cc = MFMA3216(ck##S##3, qf3, cc);                                        \
    cc = MFMA3216(ck##S##4, qf4, cc);                                        \
    cc = MFMA3216(ck##S##5, qf5, cc);                                        \
    cc = MFMA3216(ck##S##6, qf6, cc);                                        \
    cc = MFMA3216(ck##S##7, qf7, cc);                                        \
    bf16x8 fE, fO;                                                           \
    {                                                                        \
      const int sb_ = kt*128 + sq*32 + 4*hi;                                 \
      const f32x4 mA_ = *(const f32x4*)&MB[sq*32 +  0 + 4*hi];               \
      const f32x4 mB_ = *(const f32x4*)&MB[sq*32 +  8 + 4*hi];               \
      const f32x4 mC_ = *(const f32x4*)&MB[sq*32 + 16 + 4*hi];               \
      const f32x4 mD_ = *(const f32x4*)&MB[sq*32 + 24 + 4*hi];               \
      float p0  = (sb_+0  <= tgq) ? cc[0] *__expf(mA_[0]-Mq) : 0.f;          \
      float p1  = (sb_+1  <= tgq) ? cc[1] *__expf(mA_[1]-Mq) : 0.f;          \
      float p2  = (sb_+2  <= tgq) ? cc[2] *__expf(mA_[2]-Mq) : 0.f;          \
      float p3  = (sb_+3  <= tgq) ? cc[3] *__expf(mA_[3]-Mq) : 0.f;          \
      float p4  = (sb_+8  <= tgq) ? cc[4] *__expf(mB_[0]-Mq) : 0.f;          \
      float p5  = (sb_+9  <= tgq) ? cc[5] *__expf(mB_[1]-Mq) : 0.f;          \
      float p6  = (sb_+10 <= tgq) ? cc[6] *__expf(mB_[2]-Mq) : 0.f;          \
      float p7  = (sb_+11 <= tgq) ? cc[7] *__expf(mB_[3]-Mq) : 0.f;          \
      float p8  = (sb_+16 <= tgq) ? cc[8] *__expf(mC_[0]-Mq) : 0.f;          \
      float p9  = (sb_+17 <= tgq) ? cc[9] *__expf(mC_[1]-Mq) : 0.f;          \
      float p10 = (sb_+18 <= tgq) ? cc[10]*__expf(mC_[2]-Mq) : 0.f;          \
      float p11 = (sb_+19 <= tgq) ? cc[11]*__expf(mC_[3]-Mq) : 0.f;          \
      float p12 = (sb_+24 <= tgq) ? cc[12]*__expf(mD_[0]-Mq) : 0.f;          \
      float p13 = (sb_+25 <= tgq) ? cc[13]*__expf(mD_[1]-Mq) : 0.f;          \
      float p14 = (sb_+26 <= tgq) ? cc[14]*__expf(mD_[2]-Mq) : 0.f;          \
      float p15 = (sb_+27 <= tgq) ? cc[15]*__expf(mD_[3]-Mq) : 0.f;          \
      rsq += ((p0+p1)+(p2+p3))+((p4+p5)+(p6+p7))                             \
           + ((p8+p9)+(p10+p11))+((p12+p13)+(p14+p15));                      \
      unsigned A0_=cvtpk(p0,p1),  A1_=cvtpk(p2,p3);                          \
      unsigned B0_=cvtpk(p4,p5),  B1_=cvtpk(p6,p7);                          \
      unsigned C0_=cvtpk(p8,p9),  C1_=cvtpk(p10,p11);                        \
      unsigned D0_=cvtpk(p12,p13),D1_=cvtpk(p14,p15);                        \
      unsigned A0x_=(unsigned)__shfl_xor((int)A0_,32,64);                    \
      unsigned B0x_=(unsigned)__shfl_xor((int)B0_,32,64);                    \
      unsigned A1x_=(unsigned)__shfl_xor((int)A1_,32,64);                    \
      unsigned B1x_=(unsigned)__shfl_xor((int)B1_,32,64);                    \
      unsigned C0x_=(unsigned)__shfl_xor((int)C0_,32,64);                    \
      unsigned D0x_=(unsigned)__shfl_xor((int)D0_,32,64);                    \
      unsigned C1x_=(unsigned)__shfl_xor((int)C1_,32,64);                    \
      unsigned D1x_=(unsigned)__shfl_xor((int)D1_,32,64);                    \
      { unsigned* u_ = (unsigned*)&fE;                                       \
        u_[0] = hi ? B0x_ : A0_;  u_[1] = hi ? B1x_ : A1_;                   \
        u_[2] = hi ? B0_  : A0x_; u_[3] = hi ? B1_  : A1x_; }                \
      { unsigned* u_ = (unsigned*)&fO;                                       \
        u_[0] = hi ? D0x_ : C0_;  u_[1] = hi ? D1x_ : C1_;                   \
        u_[2] = hi ? D0_  : C0x_; u_[3] = hi ? D1_  : C1x_; }                \
    }                                                                        \
    a0 = MFMA3216(fE, LV9(0, sq*4 + 0 + hi), a0);                            \
    a1 = MFMA3216(fE, LV9(1, sq*4 + 0 + hi), a1);                            \
    a2 = MFMA3216(fE, LV9(2, sq*4 + 0 + hi), a2);                            \
    a3 = MFMA3216(fE, LV9(3, sq*4 + 0 + hi), a3);                            \
    a0 = MFMA3216(fO, LV9(0, sq*4 + 2 + hi), a0);                            \
    a1 = MFMA3216(fO, LV9(1, sq*4 + 2 + hi), a1);                            \
    a2 = MFMA3216(fO, LV9(2, sq*4 + 2 + hi), a2);                            \
    a3 = MFMA3216(fO, LV9(3, sq*4 + 2 + hi), a3); }

__global__ __launch_bounds__(256, 2) void mlstm_mfma9(
    const ushort* __restrict__ qb, const ushort* __restrict__ kb,
    const ushort* __restrict__ vt,
    const float* __restrict__ csb, const float* __restrict__ Mxb,
    const float* __restrict__ mbb,
    const float* __restrict__ nw, float* __restrict__ out){
  const int h = blockIdx.x;
  const int qt = 63 - blockIdx.y;            // LPT: biggest q-tile first
  const int tid = threadIdx.x, l = tid & 63;
  const int sq = tid >> 6;                   // wave = s-quarter 0..3
  const int l31 = l & 31, l15 = l & 15, hi = l >> 5;

  __shared__ __align__(16) float UNI[4*32*132];   // 67584 B: V buf / Part union
  __shared__ float MB[128];
  __shared__ float rsL[4][32];
  ushort* Vb = (ushort*)UNI;                 // 32 KB: [128 d][16 chunks]
  float*  Part = UNI;                        // [4 w][32 q][132]

  const int hS = h*S_LEN;
  const ushort* kbh = kb + h*DH;
  const ushort* vth = vt + (size_t)h*DH*S_LEN;
  const float*  mh  = mbb + hS;
  const int t0 = qt*32;
  const int NT = (t0 + 31)/128 + 1;
  const int tgq = t0 + l31;
  const float Mq = Mxb[hS + tgq];

  bf16x8 qf0,qf1,qf2,qf3,qf4,qf5,qf6,qf7;
  { const ushort* qs = qb + (size_t)tgq*E_DIM + h*DH + hi*8;
    qf0 = *(const bf16x8*)(qs+0);   qf1 = *(const bf16x8*)(qs+16);
    qf2 = *(const bf16x8*)(qs+32);  qf3 = *(const bf16x8*)(qs+48);
    qf4 = *(const bf16x8*)(qs+64);  qf5 = *(const bf16x8*)(qs+80);
    qf6 = *(const bf16x8*)(qs+96);  qf7 = *(const bf16x8*)(qs+112); }

  f32x16 a0 = Z16, a1 = Z16, a2 = Z16, a3 = Z16;
  float rsq = 0.f;

  bf16x8 ckA0,ckA1,ckA2,ckA3,ckA4,ckA5,ckA6,ckA7;
  bf16x8 ckB0,ckB1,ckB2,ckB3,ckB4,ckB5,ckB6,ckB7;

  LOADK9(0, A);
  int kt = 0;
  while (true){
    if (kt) __syncthreads();                 // prev Vb readers done
    STAGE_V9(kt);
    if (kt+1 < NT) LOADK9(kt+1, B);
    __syncthreads();                         // V(kt) landed (drains K too)
    COMPUTE9(A);
    ++kt; if (kt == NT) break;

    __syncthreads();
    STAGE_V9(kt);
    if (kt+1 < NT) LOADK9(kt+1, A);
    __syncthreads();
    COMPUTE9(B);
    ++kt; if (kt == NT) break;
  }

  // -------- epilogue: cross-wave reduce (LDS union) + normalizer + LN ------
  __syncthreads();
  #pragma unroll
  for (int r=0;r<16;++r){
    const int qrow = CROW(r) + 4*hi;
    float* pr = Part + (size_t)(sq*32 + qrow)*132 + l31;
    pr[0]  = a0[r];
    pr[32] = a1[r];
    pr[64] = a2[r];
    pr[96] = a3[r];
  }
  rsq += __shfl_xor(rsq, 32, 64);
  if (l < 32) rsL[sq][l31] = rsq;
  __syncthreads();

  {
    const int q = tid >> 3, dg = tid & 7;
    f32x4 os0={0.f,0.f,0.f,0.f}, os1=os0, os2=os0, os3=os0;
    #pragma unroll
    for (int w2=0; w2<4; ++w2){
      const float* pb = Part + (size_t)(w2*32 + q)*132 + dg*16;
      os0 += *(const f32x4*)(pb+0);
      os1 += *(const f32x4*)(pb+4);
      os2 += *(const f32x4*)(pb+8);
      os3 += *(const f32x4*)(pb+12);
    }
    const float rstot = rsL[0][q]+rsL[1][q]+rsL[2][q]+rsL[3][q];
    const int tq = t0 + q;
    const float en = __expf(-(csb[hS+tq] + Mxb[hS+tq]));
    const float iv = 1.f/(fmaxf(fabsf(rstot), en) + 1e-6f);
    f32x4 h0, h1, h2, h3;
    h0[0]=os0[0]*iv; h0[1]=os0[1]*iv; h0[2]=os0[2]*iv; h0[3]=os0[3]*iv;
    h1[0]=os1[0]*iv; h1[1]=os1[1]*iv; h1[2]=os1[2]*iv; h1[3]=os1[3]*iv;
    h2[0]=os2[0]*iv; h2[1]=os2[1]*iv; h2[2]=os2[2]*iv; h2[3]=os2[3]*iv;
    h3[0]=os3[0]*iv; h3[1]=os3[1]*iv; h3[2]=os3[2]*iv; h3[3]=os3[3]*iv;
    float s1 = (h0[0]+h0[1]+h0[2]+h0[3]) + (h1[0]+h1[1]+h1[2]+h1[3])
             + (h2[0]+h2[1]+h2[2]+h2[3]) + (h3[0]+h3[1]+h3[2]+h3[3]);
    float s2 = (h0[0]*h0[0]+h0[1]*h0[1]+h0[2]*h0[2]+h0[3]*h0[3])
             + (h1[0]*h1[0]+h1[1]*h1[1]+h1[2]*h1[2]+h1[3]*h1[3])
             + (h2[0]*h2[0]+h2[1]*h2[1]+h2[2]*h2[2]+h2[3]*h2[3])
             + (h3[0]*h3[0]+h3[1]*h3[1]+h3[2]*h3[2]+h3[3]*h3[3]);
    s1 += __shfl_xor(s1, 1, 64);  s2 += __shfl_xor(s2, 1, 64);
    s1 += __shfl_xor(s1, 2, 64);  s2 += __shfl_xor(s2, 2, 64);
    s1 += __shfl_xor(s1, 4, 64);  s2 += __shfl_xor(s2, 4, 64);
    const float mean = s1*(1.f/128.f);
    const float var  = s2*(1.f/128.f) - mean*mean;
    const float rstd = rsqrtf(var + 1e-5f);
    const float* nb = nw + h*DH + dg*16;
    const f32x4 n0 = *(const f32x4*)(nb+0);
    const f32x4 n1 = *(const f32x4*)(nb+4);
    const f32x4 n2 = *(const f32x4*)(nb+8);
    const f32x4 n3 = *(const f32x4*)(nb+12);
    float* ob = out + (size_t)tq*E_DIM + h*DH + dg*16;
    f32x4 o0v, o1v, o2v, o3v;
    o0v[0]=(h0[0]-mean)*rstd*n0[0]; o0v[1]=(h0[1]-mean)*rstd*n0[1];
    o0v[2]=(h0[2]-mean)*rstd*n0[2]; o0v[3]=(h0[3]-mean)*rstd*n0[3];
    o1v[0]=(h1[0]-mean)*rstd*n1[0]; o1v[1]=(h1[1]-mean)*rstd*n1[1];
    o1v[2]=(h1[2]-mean)*rstd*n1[2]; o1v[3]=(h1[3]-mean)*rstd*n1[3];
    o2v[0]=(h2[0]-mean)*rstd*n2[0]; o2v[1]=(h2[1]-mean)*rstd*n2[1];
    o2v[2]=(h2[2]-mean)*rstd*n2[2]; o2v[3]=(h2[3]-mean)*rstd*n2[3];
    o3v[0]=(h3[0]-mean)*rstd*n3[0]; o3v[1]=(h3[1]-mean)*rstd*n3[1];
    o3v[2]=(h3[2]-mean)*rstd*n3[2]; o3v[3]=(h3[3]-mean)*rstd*n3[3];
    *(f32x4*)(ob+0)  = o0v;
    *(f32x4*)(ob+4)  = o1v;
    *(f32x4*)(ob+8)  = o2v;
    *(f32x4*)(ob+12) = o3v;
  }
}

extern "C" void kernel_launch(void* const* d_in, const int* in_sizes, int n_in,
                              void* d_out, int out_size, void* d_ws, size_t ws_size,
                              hipStream_t stream) {
  const float* q   = (const float*)d_in[0];
  const float* k   = (const float*)d_in[1];
  const float* v   = (const float*)d_in[2];
  const float* igw = (const float*)d_in[3];
  const float* igb = (const float*)d_in[4];
  const float* fgw = (const float*)d_in[5];
  const float* fgb = (const float*)d_in[6];
  const float* nw  = (const float*)d_in[7];
  float* outp = (float*)d_out;

  float* ws  = (float*)d_ws;
  float* ig  = ws;                 // NH*S
  float* lsf = ws + 1*NHEAD*S_LEN;
  float* csb = ws + 2*NHEAD*S_LEN;
  float* Mb  = ws + 3*NHEAD*S_LEN;
  float* mbf = ws + 4*NHEAD*S_LEN;
  ushort* qbb = (ushort*)(ws + 5*NHEAD*S_LEN);          // S*E bf16 (scaled)
  ushort* kbb = qbb + (size_t)S_LEN*E_DIM;              // S*E bf16
  ushort* vtb = kbb + (size_t)S_LEN*E_DIM;              // E*S bf16 (per-head V^T)

  gates_qk<<<S_LEN/4, 256, 0, stream>>>(q, k, v, igw, igb, fgw, fgb,
                                        ig, lsf, qbb, kbb, vtb);
  scan_kernel<<<NHEAD, 256, 0, stream>>>(ig, lsf, csb, Mb, mbf);
  mlstm_mfma9<<<dim3(NHEAD, 64), 256, 0, stream>>>(qbb, kbb, vtb, csb, Mb, mbf, nw, outp);
}

// Round 18
// 74.103 us; speedup vs baseline: 1.2931x; 1.2931x over previous
//
#include <hip/hip_runtime.h>
#include <hip/hip_bf16.h>
#include <math.h>

#define S_LEN 2048
#define E_DIM 1024
#define NHEAD 8
#define DH 128
#define E3 3072

typedef short bf16x8 __attribute__((ext_vector_type(8)));
typedef short bf16x4 __attribute__((ext_vector_type(4)));
typedef float f32x4 __attribute__((ext_vector_type(4)));
typedef float f32x16 __attribute__((ext_vector_type(16)));

#define MFMA3216(a,b,c) __builtin_amdgcn_mfma_f32_32x32x16_bf16(a,b,c,0,0,0)
#define Z16 {0.f,0.f,0.f,0.f,0.f,0.f,0.f,0.f,0.f,0.f,0.f,0.f,0.f,0.f,0.f,0.f}
#define CROW(r) (((r)&3) + 8*((r)>>2))

__device__ __forceinline__ unsigned short f2bf(float f){
  union{float f; unsigned u;} x; x.f = f;
  unsigned r = x.u + 0x7FFF + ((x.u>>16)&1);
  return (unsigned short)(r>>16);
}

__device__ __forceinline__ unsigned cvtpk(float lo, float hi){
  unsigned r;
  asm("v_cvt_pk_bf16_f32 %0, %1, %2" : "=v"(r) : "v"(lo), "v"(hi));
  return r;
}

__device__ __forceinline__ float logsigf(float x){
  return fminf(x, 0.f) - log1pf(expf(-fabsf(x)));
}

typedef const __attribute__((address_space(1))) unsigned int* gas1_t;
typedef __attribute__((address_space(3))) unsigned int* las3_t;
__device__ __forceinline__ void stage16(const ushort* g, ushort* l){
  __builtin_amdgcn_global_load_lds((gas1_t)(const void*)g, (las3_t)(void*)l, 16, 0, 0);
}

// ------ Kernel A: r9's proven gates (acc[64] butterfly) + fused V^T --------
__global__ __launch_bounds__(256) void gates_qk(
    const float* __restrict__ q, const float* __restrict__ k, const float* __restrict__ v,
    const float* __restrict__ igw, const float* __restrict__ igb,
    const float* __restrict__ fgw, const float* __restrict__ fgb,
    float* __restrict__ ig_out, float* __restrict__ lsf_out,
    ushort* __restrict__ qbo, ushort* __restrict__ kbo, ushort* __restrict__ vto){
  const int t0 = blockIdx.x*4;
  const int tid = threadIdx.x;
  const int lane = tid & 63, wv = tid >> 6;
  float acc[64];
  #pragma unroll
  for (int a=0;a<64;++a) acc[a]=0.f;
  const float sc = 0.08838834764831845f;  // 1/sqrt(128)
  #pragma unroll
  for (int step=0; step<3; ++step){
    const float* src = (step==0)? q : ((step==1)? k : v);
    float4 in4[4];
    #pragma unroll
    for (int r=0;r<4;++r) in4[r] = ((const float4*)src)[(size_t)(t0+r)*256 + tid];
    if (step==0){
      #pragma unroll
      for (int r=0;r<4;++r){
        ushort4 o; o.x=f2bf(in4[r].x*sc); o.y=f2bf(in4[r].y*sc);
        o.z=f2bf(in4[r].z*sc); o.w=f2bf(in4[r].w*sc);
        ((ushort4*)qbo)[(size_t)(t0+r)*256 + tid] = o;
      }
    } else if (step==1){
      #pragma unroll
      for (int r=0;r<4;++r){
        ushort4 o; o.x=f2bf(in4[r].x); o.y=f2bf(in4[r].y);
        o.z=f2bf(in4[r].z); o.w=f2bf(in4[r].w);
        ((ushort4*)kbo)[(size_t)(t0+r)*256 + tid] = o;
      }
    } else {
      #pragma unroll
      for (int c=0;c<4;++c){
        ushort4 ov;
        ov.x = f2bf(((const float*)&in4[0])[c]);
        ov.y = f2bf(((const float*)&in4[1])[c]);
        ov.z = f2bf(((const float*)&in4[2])[c]);
        ov.w = f2bf(((const float*)&in4[3])[c]);
        *(ushort4*)(vto + (size_t)(tid*4+c)*S_LEN + t0) = ov;
      }
    }
    const int wj = step*256 + tid;
    #pragma unroll
    for (int o=0;o<8;++o){
      float4 wI = ((const float4*)igw)[o*768 + wj];
      float4 wF = ((const float4*)fgw)[o*768 + wj];
      #pragma unroll
      for (int r=0;r<4;++r){
        acc[o*4+r]    = fmaf(in4[r].x, wI.x, acc[o*4+r]);
        acc[o*4+r]    = fmaf(in4[r].y, wI.y, acc[o*4+r]);
        acc[o*4+r]    = fmaf(in4[r].z, wI.z, acc[o*4+r]);
        acc[o*4+r]    = fmaf(in4[r].w, wI.w, acc[o*4+r]);
        acc[32+o*4+r] = fmaf(in4[r].x, wF.x, acc[32+o*4+r]);
        acc[32+o*4+r] = fmaf(in4[r].y, wF.y, acc[32+o*4+r]);
        acc[32+o*4+r] = fmaf(in4[r].z, wF.z, acc[32+o*4+r]);
        acc[32+o*4+r] = fmaf(in4[r].w, wF.w, acc[32+o*4+r]);
      }
    }
  }
  int cnt = 32;
  #pragma unroll
  for (int s=0; s<6; ++s){
    const bool hib = (lane >> s) & 1;
    #pragma unroll
    for (int a=0; a<32; ++a){
      if (a < cnt){
        float sent = hib ? acc[a] : acc[a+cnt];
        float got = __shfl_xor(sent, 1<<s, 64);
        acc[a] = (hib ? acc[a+cnt] : acc[a]) + got;
      }
    }
    cnt >>= 1;
  }
  __shared__ float red[4][64];
  red[wv][lane] = acc[0];
  __syncthreads();
  if (tid < 64){
    float tot = red[0][tid]+red[1][tid]+red[2][tid]+red[3][tid];
    int a = (int)(__brev((unsigned)tid) >> 26);   // bitrev6
    int f = a >> 5, o = (a>>2)&7, r = a&3;
    int t = t0 + r;
    if (f==0) ig_out[o*S_LEN + t] = tot + igb[o];
    else      lsf_out[o*S_LEN + t] = logsigf(tot + fgb[o]);
  }
}

// ---------------- Kernel B: per-head scans ---------------------------------
__global__ __launch_bounds__(256) void scan_kernel(
    const float* __restrict__ ig, const float* __restrict__ lsf,
    float* __restrict__ cs_out, float* __restrict__ M_out, float* __restrict__ m_out){
  const int h = blockIdx.x;
  const int tid = threadIdx.x;
  __shared__ float tt[256];
  const int base = tid*8;
  const float* src = lsf + h*S_LEN;
  float loc[8]; float tot = 0.f;
  #pragma unroll
  for (int i=0;i<8;++i){ tot += src[base+i]; loc[i]=tot; }
  tt[tid]=tot; __syncthreads();
  for (int off=1; off<256; off<<=1){
    float add = (tid>=off)? tt[tid-off] : 0.f;
    __syncthreads();
    tt[tid] += add;
    __syncthreads();
  }
  const float excl = tt[tid] - tot;
  float csv[8];
  #pragma unroll
  for (int i=0;i<8;++i){ csv[i] = excl + loc[i]; cs_out[h*S_LEN+base+i]=csv[i]; }
  const float* igp = ig + h*S_LEN;
  float mloc[8], mval[8]; float mtot = -INFINITY;
  #pragma unroll
  for (int i=0;i<8;++i){
    float m = igp[base+i] - csv[i];
    mval[i] = m;
    mtot = fmaxf(mtot, m);
    mloc[i] = mtot;
  }
  __syncthreads();
  tt[tid]=mtot; __syncthreads();
  for (int off=1; off<256; off<<=1){
    float add = (tid>=off)? tt[tid-off] : -INFINITY;
    __syncthreads();
    tt[tid] = fmaxf(tt[tid], add);
    __syncthreads();
  }
  const float exclm = (tid>0)? tt[tid-1] : -INFINITY;
  #pragma unroll
  for (int i=0;i<8;++i){
    M_out[h*S_LEN+base+i] = fmaxf(exclm, mloc[i]);
    m_out[h*S_LEN+base+i] = mval[i];
  }
}

// ---- Kernel C: r15 structure + small LDS (2-stage epilogue) for occupancy -
// Part2[2][32][132] (33.8KB) unioned with K(16KB half? no: K+V as r15).
// Wait: K[32KB]+V[32KB] must fit the union too -> keep r15's K+V staging but
// shrink ONLY the epilogue buffer: union max = max(K32+V32... ) -- K and V
// are both live during compute, so the union floor is 64KB regardless.
// => Instead: V stays in LDS (32KB)+m, K stays in LDS (32KB) as r15 (proven),
// and Part2 (33.8KB) ALIASES the K+V region after compute. Union = 64.5KB?
// No gain. The actual diet: alias Part2 over K+V (64KB) -> total LDS = 64.5KB
// was r15's 67.5. Small gain only. Real diet comes from Part2 being 33.8KB
// INSIDE the same 64KB region -> LDS stays 64.5KB. So: to truly shrink, K+V
// must shrink. Use KVBLK=64 (K 16KB + V 16KB + m 256B = 32.3KB), Part2 33.8KB
// -> union 33.8KB, 4 blocks/CU. Tiles double in count but each is half-sized;
// same 2-barrier discipline.
__global__ __launch_bounds__(256, 2) void mlstm_mfma10(
    const ushort* __restrict__ qb, const ushort* __restrict__ kb,
    const ushort* __restrict__ vt,
    const float* __restrict__ csb, const float* __restrict__ Mxb,
    const float* __restrict__ mbb,
    const float* __restrict__ nw, float* __restrict__ out){
  const int h = blockIdx.x;
  const int qt = 63 - blockIdx.y;            // LPT
  const int tid = threadIdx.x, l = tid & 63;
  const int sq = tid >> 6;                   // wave = 16-s slice 0..3
  const int l31 = l & 31, l15 = l & 15, hi = l >> 5;

  __shared__ __align__(16) float UNI[8448];  // 33792 B union
  __shared__ float rsL[4][32];
  ushort* Kb = (ushort*)UNI;                 // 16 KB: [64 s][16 chunks8]
  ushort* Vb = Kb + 8192;                    // 16 KB: [128 d][8 chunks8]
  float*  MBp = UNI + 8192;                  // 64 floats (m values)
  float*  Part2 = UNI;                       // [2][32][132] epilogue alias

  const int hS = h*S_LEN;
  const ushort* kbh = kb + h*DH;
  const ushort* vth = vt + (size_t)h*DH*S_LEN;
  const float*  mh  = mbb + hS;
  const int t0 = qt*32;
  const int NT = (t0 + 31)/64 + 1;           // 64-s tiles
  const int tgq = t0 + l31;
  const float Mq = Mxb[hS + tgq];

  bf16x8 qf0,qf1,qf2,qf3,qf4,qf5,qf6,qf7;
  { const ushort* qs = qb + (size_t)tgq*E_DIM + h*DH + hi*8;
    qf0 = *(const bf16x8*)(qs+0);   qf1 = *(const bf16x8*)(qs+16);
    qf2 = *(const bf16x8*)(qs+32);  qf3 = *(const bf16x8*)(qs+48);
    qf4 = *(const bf16x8*)(qs+64);  qf5 = *(const bf16x8*)(qs+80);
    qf6 = *(const bf16x8*)(qs+96);  qf7 = *(const bf16x8*)(qs+112); }

  f32x16 a0 = Z16, a1 = Z16, a2 = Z16, a3 = Z16;
  float rsq = 0.f;

  // K tile: 64 s-rows x 128 d. Row r: 16 chunks of 8 bf16; chunk c at
  // (r*16 + (c ^ (r&15)))*8. V tile: 128 d-rows x 64 s: 8 chunks of 8;
  // chunk c of d at (d*8 + (c ^ (d&7)))*8.
#define STAGE10(ktv) {                                                       \
    _Pragma("unroll")                                                        \
    for (int i_=0;i_<4;++i_){                                                \
      const int L_ = tid + i_*256; const int row_ = L_>>4, pc_ = L_&15;      \
      stage16(kbh + (size_t)((ktv)*64+row_)*E_DIM + ((pc_^(row_&15))<<3),    \
              Kb + (size_t)L_*8); }                                          \
    _Pragma("unroll")                                                        \
    for (int i_=0;i_<4;++i_){                                                \
      const int L_ = tid + i_*256; const int d_ = L_>>3, pc_ = L_&7;         \
      stage16(vth + (size_t)d_*S_LEN + (ktv)*64 + ((pc_^(d_&7))<<3),         \
              Vb + (size_t)L_*8); }                                          \
    if (tid < 16)                                                            \
      stage16((const ushort*)(mh + (ktv)*64) + tid*8,                        \
              (ushort*)MBp + tid*8); }

  // QK: wave sq handles s-slice sq*16 of the 64; rows r = sq*16 + l15? No:
  // 32x32 MFMA needs 32 s-rows per wave; with 64-s tiles, waves sq=0..1
  // cover s 0..31 / 32..63 for qh? We have 4 waves and 64 s-rows = 2 waves
  // worth. Assign: waves 0,2 -> s 0..31; waves 1,3 -> s 32..63; the pair
  // (0,2),(1,3) split the K=128 contraction dim in half (64 each) and the
  // partial P sums combine in the existing cross-wave Osum reduction? NO -
  // P must be complete before exp. Instead waves split d: QK contraction
  // over full d=128 per wave; waves 0,1 own s-halves for QK AND PV d-halves.
  // Simpler: wave w owns s-half (w&1)*32; compute FULL QK for those 32 s
  // (8 MFMA); PV: wave w accumulates only d-half (w>>1)*64 (4 MFMA over its
  // 32 s). Each (s,q) P computed by 2 waves (w and w^2) redundantly - 2x QK
  // work vs r15 but tiles half size; epilogue reduces over 2 partials
  // (s-halves) per d-half -> Part2[2] indexed by s-half, waves 2,3 add.
  const int sh = sq & 1;                     // s-half 0/1
  const int dh2 = sq >> 1;                   // d-half 0/1

  STAGE10(0);
  for (int kt=0; kt<NT; ++kt){
    if (kt) __syncthreads();
    else    __syncthreads();
    if (false) {}
    // stage(kt) landed
    {
      const ushort* kbase = Kb + (size_t)(sh*32 + l31)*128;
      f32x16 cc = Z16;
      { bf16x8 ka;
        ka = *(const bf16x8*)(kbase + (((0*2+hi)^l15)<<3)); cc = MFMA3216(ka, qf0, cc);
        ka = *(const bf16x8*)(kbase + (((1*2+hi)^l15)<<3)); cc = MFMA3216(ka, qf1, cc);
        ka = *(const bf16x8*)(kbase + (((2*2+hi)^l15)<<3)); cc = MFMA3216(ka, qf2, cc);
        ka = *(const bf16x8*)(kbase + (((3*2+hi)^l15)<<3)); cc = MFMA3216(ka, qf3, cc);
        ka = *(const bf16x8*)(kbase + (((4*2+hi)^l15)<<3)); cc = MFMA3216(ka, qf4, cc);
        ka = *(const bf16x8*)(kbase + (((5*2+hi)^l15)<<3)); cc = MFMA3216(ka, qf5, cc);
        ka = *(const bf16x8*)(kbase + (((6*2+hi)^l15)<<3)); cc = MFMA3216(ka, qf6, cc);
        ka = *(const bf16x8*)(kbase + (((7*2+hi)^l15)<<3)); cc = MFMA3216(ka, qf7, cc); }

      bf16x8 fE, fO;
      {
        const int sb_ = kt*64 + sh*32 + 4*hi;
        const f32x4 mA_ = *(const f32x4*)&MBp[sh*32 +  0 + 4*hi];
        const f32x4 mB_ = *(const f32x4*)&MBp[sh*32 +  8 + 4*hi];
        const f32x4 mC_ = *(const f32x4*)&MBp[sh*32 + 16 + 4*hi];
        const f32x4 mD_ = *(const f32x4*)&MBp[sh*32 + 24 + 4*hi];
        float p0  = (sb_+0  <= tgq) ? cc[0] *__expf(mA_[0]-Mq) : 0.f;
        float p1  = (sb_+1  <= tgq) ? cc[1] *__expf(mA_[1]-Mq) : 0.f;
        float p2  = (sb_+2  <= tgq) ? cc[2] *__expf(mA_[2]-Mq) : 0.f;
        float p3  = (sb_+3  <= tgq) ? cc[3] *__expf(mA_[3]-Mq) : 0.f;
        float p4  = (sb_+8  <= tgq) ? cc[4] *__expf(mB_[0]-Mq) : 0.f;
        float p5  = (sb_+9  <= tgq) ? cc[5] *__expf(mB_[1]-Mq) : 0.f;
        float p6  = (sb_+10 <= tgq) ? cc[6] *__expf(mB_[2]-Mq) : 0.f;
        float p7  = (sb_+11 <= tgq) ? cc[7] *__expf(mB_[3]-Mq) : 0.f;
        float p8  = (sb_+16 <= tgq) ? cc[8] *__expf(mC_[0]-Mq) : 0.f;
        float p9  = (sb_+17 <= tgq) ? cc[9] *__expf(mC_[1]-Mq) : 0.f;
        float p10 = (sb_+18 <= tgq) ? cc[10]*__expf(mC_[2]-Mq) : 0.f;
        float p11 = (sb_+19 <= tgq) ? cc[11]*__expf(mC_[3]-Mq) : 0.f;
        float p12 = (sb_+24 <= tgq) ? cc[12]*__expf(mD_[0]-Mq) : 0.f;
        float p13 = (sb_+25 <= tgq) ? cc[13]*__expf(mD_[1]-Mq) : 0.f;
        float p14 = (sb_+26 <= tgq) ? cc[14]*__expf(mD_[2]-Mq) : 0.f;
        float p15 = (sb_+27 <= tgq) ? cc[15]*__expf(mD_[3]-Mq) : 0.f;
        if (dh2 == 0)
          rsq += ((p0+p1)+(p2+p3))+((p4+p5)+(p6+p7))
               + ((p8+p9)+(p10+p11))+((p12+p13)+(p14+p15));
        unsigned A0_=cvtpk(p0,p1),  A1_=cvtpk(p2,p3);
        unsigned B0_=cvtpk(p4,p5),  B1_=cvtpk(p6,p7);
        unsigned C0_=cvtpk(p8,p9),  C1_=cvtpk(p10,p11);
        unsigned D0_=cvtpk(p12,p13),D1_=cvtpk(p14,p15);
        unsigned A0x_=(unsigned)__shfl_xor((int)A0_,32,64);
        unsigned B0x_=(unsigned)__shfl_xor((int)B0_,32,64);
        unsigned A1x_=(unsigned)__shfl_xor((int)A1_,32,64);
        unsigned B1x_=(unsigned)__shfl_xor((int)B1_,32,64);
        unsigned C0x_=(unsigned)__shfl_xor((int)C0_,32,64);
        unsigned D0x_=(unsigned)__shfl_xor((int)D0_,32,64);
        unsigned C1x_=(unsigned)__shfl_xor((int)C1_,32,64);
        unsigned D1x_=(unsigned)__shfl_xor((int)D1_,32,64);
        { unsigned* u_ = (unsigned*)&fE;
          u_[0] = hi ? B0x_ : A0_;  u_[1] = hi ? B1x_ : A1_;
          u_[2] = hi ? B0_  : A0x_; u_[3] = hi ? B1_  : A1x_; }
        { unsigned* u_ = (unsigned*)&fO;
          u_[0] = hi ? D0x_ : C0_;  u_[1] = hi ? D1x_ : C1_;
          u_[2] = hi ? D0_  : C0x_; u_[3] = hi ? D1_  : C1x_; }
      }

      // PV: this wave's d-half (4x 32-d blocks -> dh2*64..+63), s-slice
      // sh*32..+31, K=16 per frag (ks = sh*4 + 2*kpair + hi over 64 s? No:
      // V chunks: s-chunk cs covers s = cs*8..+7; wave needs s range
      // sh*32..+31 -> cs in {sh*4 + 0..3}; frag fE covers s offsets 0..15
      // (cs sh*4+{0,1}+hi pattern), fO 16..31.
#define LV10(dt, cs) (*(const bf16x8*)(Vb + (size_t)((dh2*2+(dt))*32+l31)*64 + (((cs)^((((dh2*2+(dt))*32+l31)&7)))<<3)))
      a0 = MFMA3216(fE, LV10(0, sh*4 + 0 + hi), a0);
      a1 = MFMA3216(fE, LV10(1, sh*4 + 0 + hi), a1);
      a0 = MFMA3216(fO, LV10(0, sh*4 + 2 + hi), a0);
      a1 = MFMA3216(fO, LV10(1, sh*4 + 2 + hi), a1);
#undef LV10
    }
    __syncthreads();                       // K/V reads done
    if (kt+1 < NT){ STAGE10(kt+1); }
  }

  // -------- epilogue: 2-stage (write halves, accumulate, read) -------------
  __syncthreads();
  if (sq < 2){                             // sh = sq, dh2 = 0: d 0..63
    #pragma unroll
    for (int r=0;r<16;++r){
      const int qrow = CROW(r) + 4*hi;
      float* pr = Part2 + (size_t)(sh*32 + qrow)*132 + l31;
      pr[0]  = a0[r];
      pr[32] = a1[r];
      pr[64] = 0.f;
      pr[96] = 0.f;
    }
  }
  rsq += __shfl_xor(rsq, 32, 64);
  if (l < 32) rsL[sq][l31] = rsq;
  __syncthreads();
  if (sq >= 2){                            // dh2 = 1: d 64..127 into cols 64/96
    #pragma unroll
    for (int r=0;r<16;++r){
      const int qrow = CROW(r) + 4*hi;
      float* pr = Part2 + (size_t)(sh*32 + qrow)*132 + l31;
      pr[64] = a0[r];
      pr[96] = a1[r];
    }
  }
  __syncthreads();

  {
    const int q = tid >> 3, dg = tid & 7;
    f32x4 os0={0.f,0.f,0.f,0.f}, os1=os0, os2=os0, os3=os0;
    #pragma unroll
    for (int w2=0; w2<2; ++w2){
      const float* pb = Part2 + (size_t)(w2*32 + q)*132 + dg*16;
      os0 += *(const f32x4*)(pb+0);
      os1 += *(const f32x4*)(pb+4);
      os2 += *(const f32x4*)(pb+8);
      os3 += *(const f32x4*)(pb+12);
    }
    const float rstot = rsL[0][q]+rsL[1][q];
    const int tq = t0 + q;
    const float en = __expf(-(csb[hS+tq] + Mxb[hS+tq]));
    const float iv = 1.f/(fmaxf(fabsf(rstot), en) + 1e-6f);
    f32x4 h0, h1, h2, h3;
    h0[0]=os0[0]*iv; h0[1]=os0[1]*iv; h0[2]=os0[2]*iv; h0[3]=os0[3]*iv;
    h1[0]=os1[0]*iv; h1[1]=os1[1]*iv; h1[2]=os1[2]*iv; h1[3]=os1[3]*iv;
    h2[0]=os2[0]*iv; h2[1]=os2[1]*iv; h2[2]=os2[2]*iv; h2[3]=os2[3]*iv;
    h3[0]=os3[0]*iv; h3[1]=os3[1]*iv; h3[2]=os3[2]*iv; h3[3]=os3[3]*iv;
    float s1 = (h0[0]+h0[1]+h0[2]+h0[3]) + (h1[0]+h1[1]+h1[2]+h1[3])
             + (h2[0]+h2[1]+h2[2]+h2[3]) + (h3[0]+h3[1]+h3[2]+h3[3]);
    float s2 = (h0[0]*h0[0]+h0[1]*h0[1]+h0[2]*h0[2]+h0[3]*h0[3])
             + (h1[0]*h1[0]+h1[1]*h1[1]+h1[2]*h1[2]+h1[3]*h1[3])
             + (h2[0]*h2[0]+h2[1]*h2[1]+h2[2]*h2[2]+h2[3]*h2[3])
             + (h3[0]*h3[0]+h3[1]*h3[1]+h3[2]*h3[2]+h3[3]*h3[3]);
    s1 += __shfl_xor(s1, 1, 64);  s2 += __shfl_xor(s2, 1, 64);
    s1 += __shfl_xor(s1, 2, 64);  s2 += __shfl_xor(s2, 2, 64);
    s1 += __shfl_xor(s1, 4, 64);  s2 += __shfl_xor(s2, 4, 64);
    const float mean = s1*(1.f/128.f);
    const float var  = s2*(1.f/128.f) - mean*mean;
    const float rstd = rsqrtf(var + 1e-5f);
    const float* nb = nw + h*DH + dg*16;
    const f32x4 n0 = *(const f32x4*)(nb+0);
    const f32x4 n1 = *(const f32x4*)(nb+4);
    const f32x4 n2 = *(const f32x4*)(nb+8);
    const f32x4 n3 = *(const f32x4*)(nb+12);
    float* ob = out + (size_t)tq*E_DIM + h*DH + dg*16;
    f32x4 o0v, o1v, o2v, o3v;
    o0v[0]=(h0[0]-mean)*rstd*n0[0]; o0v[1]=(h0[1]-mean)*rstd*n0[1];
    o0v[2]=(h0[2]-mean)*rstd*n0[2]; o0v[3]=(h0[3]-mean)*rstd*n0[3];
    o1v[0]=(h1[0]-mean)*rstd*n1[0]; o1v[1]=(h1[1]-mean)*rstd*n1[1];
    o1v[2]=(h1[2]-mean)*rstd*n1[2]; o1v[3]=(h1[3]-mean)*rstd*n1[3];
    o2v[0]=(h2[0]-mean)*rstd*n2[0]; o2v[1]=(h2[1]-mean)*rstd*n2[1];
    o2v[2]=(h2[2]-mean)*rstd*n2[2]; o2v[3]=(h2[3]-mean)*rstd*n2[3];
    o3v[0]=(h3[0]-mean)*rstd*n3[0]; o3v[1]=(h3[1]-mean)*rstd*n3[1];
    o3v[2]=(h3[2]-mean)*rstd*n3[2]; o3v[3]=(h3[3]-mean)*rstd*n3[3];
    *(f32x4*)(ob+0)  = o0v;
    *(f32x4*)(ob+4)  = o1v;
    *(f32x4*)(ob+8)  = o2v;
    *(f32x4*)(ob+12) = o3v;
  }
}

extern "C" void kernel_launch(void* const* d_in, const int* in_sizes, int n_in,
                              void* d_out, int out_size, void* d_ws, size_t ws_size,
                              hipStream_t stream) {
  const float* q   = (const float*)d_in[0];
  const float* k   = (const float*)d_in[1];
  const float* v   = (const float*)d_in[2];
  const float* igw = (const float*)d_in[3];
  const float* igb = (const float*)d_in[4];
  const float* fgw = (const float*)d_in[5];
  const float* fgb = (const float*)d_in[6];
  const float* nw  = (const float*)d_in[7];
  float* outp = (float*)d_out;

  float* ws  = (float*)d_ws;
  float* ig  = ws;                 // NH*S
  float* lsf = ws + 1*NHEAD*S_LEN;
  float* csb = ws + 2*NHEAD*S_LEN;
  float* Mb  = ws + 3*NHEAD*S_LEN;
  float* mbf = ws + 4*NHEAD*S_LEN;
  ushort* qbb = (ushort*)(ws + 5*NHEAD*S_LEN);          // S*E bf16 (scaled)
  ushort* kbb = qbb + (size_t)S_LEN*E_DIM;              // S*E bf16
  ushort* vtb = kbb + (size_t)S_LEN*E_DIM;              // E*S bf16 (per-head V^T)

  gates_qk<<<S_LEN/4, 256, 0, stream>>>(q, k, v, igw, igb, fgw, fgb,
                                        ig, lsf, qbb, kbb, vtb);
  scan_kernel<<<NHEAD, 256, 0, stream>>>(ig, lsf, csb, Mb, mbf);
  mlstm_mfma10<<<dim3(NHEAD, 64), 256, 0, stream>>>(qbb, kbb, vtb, csb, Mb, mbf, nw, outp);
}

// Round 19
// 61.193 us; speedup vs baseline: 1.5659x; 1.2110x over previous
//
#include <hip/hip_runtime.h>
#include <hip/hip_bf16.h>
#include <math.h>

#define S_LEN 2048
#define E_DIM 1024
#define NHEAD 8
#define DH 128
#define E3 3072

typedef short bf16x8 __attribute__((ext_vector_type(8)));
typedef short bf16x4 __attribute__((ext_vector_type(4)));
typedef float f32x4 __attribute__((ext_vector_type(4)));
typedef float f32x16 __attribute__((ext_vector_type(16)));

#define MFMA3216(a,b,c) __builtin_amdgcn_mfma_f32_32x32x16_bf16(a,b,c,0,0,0)
#define Z16 {0.f,0.f,0.f,0.f,0.f,0.f,0.f,0.f,0.f,0.f,0.f,0.f,0.f,0.f,0.f,0.f}
#define CROW(r) (((r)&3) + 8*((r)>>2))

__device__ __forceinline__ unsigned short f2bf(float f){
  union{float f; unsigned u;} x; x.f = f;
  unsigned r = x.u + 0x7FFF + ((x.u>>16)&1);
  return (unsigned short)(r>>16);
}

__device__ __forceinline__ unsigned cvtpk(float lo, float hi){
  unsigned r;
  asm("v_cvt_pk_bf16_f32 %0, %1, %2" : "=v"(r) : "v"(lo), "v"(hi));
  return r;
}

__device__ __forceinline__ float logsigf(float x){
  return fminf(x, 0.f) - log1pf(expf(-fabsf(x)));
}

typedef const __attribute__((address_space(1))) unsigned int* gas1_t;
typedef __attribute__((address_space(3))) unsigned int* las3_t;
__device__ __forceinline__ void stage16(const ushort* g, ushort* l){
  __builtin_amdgcn_global_load_lds((gas1_t)(const void*)g, (las3_t)(void*)l, 16, 0, 0);
}

// ------ Kernel A: gates (acc[64] butterfly, single-pass inputs) + V^T ------
__global__ __launch_bounds__(256) void gates_qk(
    const float* __restrict__ q, const float* __restrict__ k, const float* __restrict__ v,
    const float* __restrict__ igw, const float* __restrict__ igb,
    const float* __restrict__ fgw, const float* __restrict__ fgb,
    float* __restrict__ ig_out, float* __restrict__ lsf_out,
    ushort* __restrict__ qbo, ushort* __restrict__ kbo, ushort* __restrict__ vto){
  const int t0 = blockIdx.x*4;
  const int tid = threadIdx.x;
  const int lane = tid & 63, wv = tid >> 6;
  float acc[64];
  #pragma unroll
  for (int a=0;a<64;++a) acc[a]=0.f;
  const float sc = 0.08838834764831845f;  // 1/sqrt(128)
  #pragma unroll
  for (int step=0; step<3; ++step){
    const float* src = (step==0)? q : ((step==1)? k : v);
    float4 in4[4];
    #pragma unroll
    for (int r=0;r<4;++r) in4[r] = ((const float4*)src)[(size_t)(t0+r)*256 + tid];
    if (step==0){
      #pragma unroll
      for (int r=0;r<4;++r){
        ushort4 o; o.x=f2bf(in4[r].x*sc); o.y=f2bf(in4[r].y*sc);
        o.z=f2bf(in4[r].z*sc); o.w=f2bf(in4[r].w*sc);
        ((ushort4*)qbo)[(size_t)(t0+r)*256 + tid] = o;
      }
    } else if (step==1){
      #pragma unroll
      for (int r=0;r<4;++r){
        ushort4 o; o.x=f2bf(in4[r].x); o.y=f2bf(in4[r].y);
        o.z=f2bf(in4[r].z); o.w=f2bf(in4[r].w);
        ((ushort4*)kbo)[(size_t)(t0+r)*256 + tid] = o;
      }
    } else {
      // fused V^T: d = tid*4+c (global over E == h*DH+dloc), 4 t-rows -> 8B
      #pragma unroll
      for (int c=0;c<4;++c){
        ushort4 ov;
        ov.x = f2bf(((const float*)&in4[0])[c]);
        ov.y = f2bf(((const float*)&in4[1])[c]);
        ov.z = f2bf(((const float*)&in4[2])[c]);
        ov.w = f2bf(((const float*)&in4[3])[c]);
        *(ushort4*)(vto + (size_t)(tid*4+c)*S_LEN + t0) = ov;
      }
    }
    const int wj = step*256 + tid;
    #pragma unroll
    for (int o=0;o<8;++o){
      float4 wI = ((const float4*)igw)[o*768 + wj];
      float4 wF = ((const float4*)fgw)[o*768 + wj];
      #pragma unroll
      for (int r=0;r<4;++r){
        acc[o*4+r]    = fmaf(in4[r].x, wI.x, acc[o*4+r]);
        acc[o*4+r]    = fmaf(in4[r].y, wI.y, acc[o*4+r]);
        acc[o*4+r]    = fmaf(in4[r].z, wI.z, acc[o*4+r]);
        acc[o*4+r]    = fmaf(in4[r].w, wI.w, acc[o*4+r]);
        acc[32+o*4+r] = fmaf(in4[r].x, wF.x, acc[32+o*4+r]);
        acc[32+o*4+r] = fmaf(in4[r].y, wF.y, acc[32+o*4+r]);
        acc[32+o*4+r] = fmaf(in4[r].z, wF.z, acc[32+o*4+r]);
        acc[32+o*4+r] = fmaf(in4[r].w, wF.w, acc[32+o*4+r]);
      }
    }
  }
  int cnt = 32;
  #pragma unroll
  for (int s=0; s<6; ++s){
    const bool hib = (lane >> s) & 1;
    #pragma unroll
    for (int a=0; a<32; ++a){
      if (a < cnt){
        float sent = hib ? acc[a] : acc[a+cnt];
        float got = __shfl_xor(sent, 1<<s, 64);
        acc[a] = (hib ? acc[a+cnt] : acc[a]) + got;
      }
    }
    cnt >>= 1;
  }
  __shared__ float red[4][64];
  red[wv][lane] = acc[0];
  __syncthreads();
  if (tid < 64){
    float tot = red[0][tid]+red[1][tid]+red[2][tid]+red[3][tid];
    int a = (int)(__brev((unsigned)tid) >> 26);   // bitrev6
    int f = a >> 5, o = (a>>2)&7, r = a&3;
    int t = t0 + r;
    if (f==0) ig_out[o*S_LEN + t] = tot + igb[o];
    else      lsf_out[o*S_LEN + t] = logsigf(tot + fgb[o]);
  }
}

// ---------------- Kernel B: per-head scans ---------------------------------
__global__ __launch_bounds__(256) void scan_kernel(
    const float* __restrict__ ig, const float* __restrict__ lsf,
    float* __restrict__ cs_out, float* __restrict__ M_out, float* __restrict__ m_out){
  const int h = blockIdx.x;
  const int tid = threadIdx.x;
  __shared__ float tt[256];
  const int base = tid*8;
  const float* src = lsf + h*S_LEN;
  float loc[8]; float tot = 0.f;
  #pragma unroll
  for (int i=0;i<8;++i){ tot += src[base+i]; loc[i]=tot; }
  tt[tid]=tot; __syncthreads();
  for (int off=1; off<256; off<<=1){
    float add = (tid>=off)? tt[tid-off] : 0.f;
    __syncthreads();
    tt[tid] += add;
    __syncthreads();
  }
  const float excl = tt[tid] - tot;
  float csv[8];
  #pragma unroll
  for (int i=0;i<8;++i){ csv[i] = excl + loc[i]; cs_out[h*S_LEN+base+i]=csv[i]; }
  const float* igp = ig + h*S_LEN;
  float mloc[8], mval[8]; float mtot = -INFINITY;
  #pragma unroll
  for (int i=0;i<8;++i){
    float m = igp[base+i] - csv[i];
    mval[i] = m;
    mtot = fmaxf(mtot, m);
    mloc[i] = mtot;
  }
  __syncthreads();
  tt[tid]=mtot; __syncthreads();
  for (int off=1; off<256; off<<=1){
    float add = (tid>=off)? tt[tid-off] : -INFINITY;
    __syncthreads();
    tt[tid] = fmaxf(tt[tid], add);
    __syncthreads();
  }
  const float exclm = (tid>0)? tt[tid-1] : -INFINITY;
  #pragma unroll
  for (int i=0;i<8;++i){
    M_out[h*S_LEN+base+i] = fmaxf(exclm, mloc[i]);
    m_out[h*S_LEN+base+i] = mval[i];
  }
}

// ---------------- Kernel C: r15 measured-best + T5 setprio -----------------
__global__ __launch_bounds__(256, 2) void mlstm_mfma6(
    const ushort* __restrict__ qb, const ushort* __restrict__ kb,
    const ushort* __restrict__ vt,
    const float* __restrict__ csb, const float* __restrict__ Mxb,
    const float* __restrict__ mbb,
    const float* __restrict__ nw, float* __restrict__ out){
  const int h = blockIdx.x;
  const int qt = 63 - blockIdx.y;            // LPT: biggest q-tile first
  const int tid = threadIdx.x, l = tid & 63;
  const int sq = tid >> 6;                   // wave = s-quarter 0..3
  const int l31 = l & 31, l15 = l & 15, hi = l >> 5;

  __shared__ __align__(16) float UNI[4*32*132];   // 67584 B union
  __shared__ float MB[128];
  __shared__ float rsL[4][32];
  ushort* Kb = (ushort*)UNI;                 // 32 KB: [128 s][16 chunks]
  ushort* Vb = Kb + 16384;                   // 32 KB: [128 d][16 chunks]
  float*  Part = UNI;                        // [4 w][32 q][132]

  const int hS = h*S_LEN;
  const ushort* kbh = kb + h*DH;
  const ushort* vth = vt + (size_t)h*DH*S_LEN;
  const float*  mh  = mbb + hS;
  const int t0 = qt*32;
  const int NT = (t0 + 31)/128 + 1;
  const int tgq = t0 + l31;
  const float Mq = Mxb[hS + tgq];

  bf16x8 qf0,qf1,qf2,qf3,qf4,qf5,qf6,qf7;
  { const ushort* qs = qb + (size_t)tgq*E_DIM + h*DH + hi*8;
    qf0 = *(const bf16x8*)(qs+0);   qf1 = *(const bf16x8*)(qs+16);
    qf2 = *(const bf16x8*)(qs+32);  qf3 = *(const bf16x8*)(qs+48);
    qf4 = *(const bf16x8*)(qs+64);  qf5 = *(const bf16x8*)(qs+80);
    qf6 = *(const bf16x8*)(qs+96);  qf7 = *(const bf16x8*)(qs+112); }

  f32x16 a0 = Z16, a1 = Z16, a2 = Z16, a3 = Z16;
  float rsq = 0.f;

#define STAGE6(ktv) {                                                        \
    _Pragma("unroll")                                                        \
    for (int i_=0;i_<8;++i_){                                                \
      const int L_ = tid + i_*256; const int row_ = L_>>4, pc_ = L_&15;      \
      stage16(kbh + (size_t)((ktv)*128+row_)*E_DIM + ((pc_^(row_&15))<<3),   \
              Kb + (size_t)L_*8); }                                          \
    _Pragma("unroll")                                                        \
    for (int i_=0;i_<8;++i_){                                                \
      const int L_ = tid + i_*256; const int d_ = L_>>4, pc_ = L_&15;        \
      stage16(vth + (size_t)d_*S_LEN + (ktv)*128 + ((pc_^(d_&15))<<3),       \
              Vb + (size_t)L_*8); }                                          \
    if (tid < 32)                                                            \
      stage16((const ushort*)(mh + (ktv)*128) + tid*8,                       \
              (ushort*)MB + tid*8); }

#define LV6(dt, cs) (*(const bf16x8*)(Vb + (size_t)((dt)*32+l31)*128 + (((cs)^l15)<<3)))

  for (int kt=0; kt<NT; ++kt){
    if (kt) __syncthreads();                 // prev tile's LDS readers done
    STAGE6(kt);
    __syncthreads();                         // stage landed (vmcnt drained)

    __builtin_amdgcn_s_setprio(1);           // T5: favor compute waves while
                                             // the co-resident block stages
    const ushort* kbase = Kb + (size_t)(sq*32 + l31)*128;
    f32x16 cc = Z16;
    { bf16x8 ka;
      ka = *(const bf16x8*)(kbase + (((0*2+hi)^l15)<<3)); cc = MFMA3216(ka, qf0, cc);
      ka = *(const bf16x8*)(kbase + (((1*2+hi)^l15)<<3)); cc = MFMA3216(ka, qf1, cc);
      ka = *(const bf16x8*)(kbase + (((2*2+hi)^l15)<<3)); cc = MFMA3216(ka, qf2, cc);
      ka = *(const bf16x8*)(kbase + (((3*2+hi)^l15)<<3)); cc = MFMA3216(ka, qf3, cc);
      ka = *(const bf16x8*)(kbase + (((4*2+hi)^l15)<<3)); cc = MFMA3216(ka, qf4, cc);
      ka = *(const bf16x8*)(kbase + (((5*2+hi)^l15)<<3)); cc = MFMA3216(ka, qf5, cc);
      ka = *(const bf16x8*)(kbase + (((6*2+hi)^l15)<<3)); cc = MFMA3216(ka, qf6, cc);
      ka = *(const bf16x8*)(kbase + (((7*2+hi)^l15)<<3)); cc = MFMA3216(ka, qf7, cc); }

    bf16x8 fE, fO;
    {
      const int sb_ = kt*128 + sq*32 + 4*hi;
      const f32x4 mA_ = *(const f32x4*)&MB[sq*32 +  0 + 4*hi];
      const f32x4 mB_ = *(const f32x4*)&MB[sq*32 +  8 + 4*hi];
      const f32x4 mC_ = *(const f32x4*)&MB[sq*32 + 16 + 4*hi];
      const f32x4 mD_ = *(const f32x4*)&MB[sq*32 + 24 + 4*hi];
      float p0  = (sb_+0  <= tgq) ? cc[0] *__expf(mA_[0]-Mq) : 0.f;
      float p1  = (sb_+1  <= tgq) ? cc[1] *__expf(mA_[1]-Mq) : 0.f;
      float p2  = (sb_+2  <= tgq) ? cc[2] *__expf(mA_[2]-Mq) : 0.f;
      float p3  = (sb_+3  <= tgq) ? cc[3] *__expf(mA_[3]-Mq) : 0.f;
      float p4  = (sb_+8  <= tgq) ? cc[4] *__expf(mB_[0]-Mq) : 0.f;
      float p5  = (sb_+9  <= tgq) ? cc[5] *__expf(mB_[1]-Mq) : 0.f;
      float p6  = (sb_+10 <= tgq) ? cc[6] *__expf(mB_[2]-Mq) : 0.f;
      float p7  = (sb_+11 <= tgq) ? cc[7] *__expf(mB_[3]-Mq) : 0.f;
      float p8  = (sb_+16 <= tgq) ? cc[8] *__expf(mC_[0]-Mq) : 0.f;
      float p9  = (sb_+17 <= tgq) ? cc[9] *__expf(mC_[1]-Mq) : 0.f;
      float p10 = (sb_+18 <= tgq) ? cc[10]*__expf(mC_[2]-Mq) : 0.f;
      float p11 = (sb_+19 <= tgq) ? cc[11]*__expf(mC_[3]-Mq) : 0.f;
      float p12 = (sb_+24 <= tgq) ? cc[12]*__expf(mD_[0]-Mq) : 0.f;
      float p13 = (sb_+25 <= tgq) ? cc[13]*__expf(mD_[1]-Mq) : 0.f;
      float p14 = (sb_+26 <= tgq) ? cc[14]*__expf(mD_[2]-Mq) : 0.f;
      float p15 = (sb_+27 <= tgq) ? cc[15]*__expf(mD_[3]-Mq) : 0.f;
      rsq += ((p0+p1)+(p2+p3))+((p4+p5)+(p6+p7))
           + ((p8+p9)+(p10+p11))+((p12+p13)+(p14+p15));
      unsigned A0_=cvtpk(p0,p1),  A1_=cvtpk(p2,p3);
      unsigned B0_=cvtpk(p4,p5),  B1_=cvtpk(p6,p7);
      unsigned C0_=cvtpk(p8,p9),  C1_=cvtpk(p10,p11);
      unsigned D0_=cvtpk(p12,p13),D1_=cvtpk(p14,p15);
      unsigned A0x_=(unsigned)__shfl_xor((int)A0_,32,64);
      unsigned B0x_=(unsigned)__shfl_xor((int)B0_,32,64);
      unsigned A1x_=(unsigned)__shfl_xor((int)A1_,32,64);
      unsigned B1x_=(unsigned)__shfl_xor((int)B1_,32,64);
      unsigned C0x_=(unsigned)__shfl_xor((int)C0_,32,64);
      unsigned D0x_=(unsigned)__shfl_xor((int)D0_,32,64);
      unsigned C1x_=(unsigned)__shfl_xor((int)C1_,32,64);
      unsigned D1x_=(unsigned)__shfl_xor((int)D1_,32,64);
      { unsigned* u_ = (unsigned*)&fE;
        u_[0] = hi ? B0x_ : A0_;  u_[1] = hi ? B1x_ : A1_;
        u_[2] = hi ? B0_  : A0x_; u_[3] = hi ? B1_  : A1x_; }
      { unsigned* u_ = (unsigned*)&fO;
        u_[0] = hi ? D0x_ : C0_;  u_[1] = hi ? D1x_ : C1_;
        u_[2] = hi ? D0_  : C0x_; u_[3] = hi ? D1_  : C1x_; }
    }

    a0 = MFMA3216(fE, LV6(0, sq*4 + 0 + hi), a0);
    a1 = MFMA3216(fE, LV6(1, sq*4 + 0 + hi), a1);
    a2 = MFMA3216(fE, LV6(2, sq*4 + 0 + hi), a2);
    a3 = MFMA3216(fE, LV6(3, sq*4 + 0 + hi), a3);
    a0 = MFMA3216(fO, LV6(0, sq*4 + 2 + hi), a0);
    a1 = MFMA3216(fO, LV6(1, sq*4 + 2 + hi), a1);
    a2 = MFMA3216(fO, LV6(2, sq*4 + 2 + hi), a2);
    a3 = MFMA3216(fO, LV6(3, sq*4 + 2 + hi), a3);
    __builtin_amdgcn_s_setprio(0);
  }

  // -------- epilogue: cross-wave reduce (LDS union) + normalizer + LN ------
  __syncthreads();
  #pragma unroll
  for (int r=0;r<16;++r){
    const int qrow = CROW(r) + 4*hi;
    float* pr = Part + (size_t)(sq*32 + qrow)*132 + l31;
    pr[0]  = a0[r];
    pr[32] = a1[r];
    pr[64] = a2[r];
    pr[96] = a3[r];
  }
  rsq += __shfl_xor(rsq, 32, 64);
  if (l < 32) rsL[sq][l31] = rsq;
  __syncthreads();

  {
    const int q = tid >> 3, dg = tid & 7;
    f32x4 os0={0.f,0.f,0.f,0.f}, os1=os0, os2=os0, os3=os0;
    #pragma unroll
    for (int w2=0; w2<4; ++w2){
      const float* pb = Part + (size_t)(w2*32 + q)*132 + dg*16;
      os0 += *(const f32x4*)(pb+0);
      os1 += *(const f32x4*)(pb+4);
      os2 += *(const f32x4*)(pb+8);
      os3 += *(const f32x4*)(pb+12);
    }
    const float rstot = rsL[0][q]+rsL[1][q]+rsL[2][q]+rsL[3][q];
    const int tq = t0 + q;
    const float en = __expf(-(csb[hS+tq] + Mxb[hS+tq]));
    const float iv = 1.f/(fmaxf(fabsf(rstot), en) + 1e-6f);
    f32x4 h0, h1, h2, h3;
    h0[0]=os0[0]*iv; h0[1]=os0[1]*iv; h0[2]=os0[2]*iv; h0[3]=os0[3]*iv;
    h1[0]=os1[0]*iv; h1[1]=os1[1]*iv; h1[2]=os1[2]*iv; h1[3]=os1[3]*iv;
    h2[0]=os2[0]*iv; h2[1]=os2[1]*iv; h2[2]=os2[2]*iv; h2[3]=os2[3]*iv;
    h3[0]=os3[0]*iv; h3[1]=os3[1]*iv; h3[2]=os3[2]*iv; h3[3]=os3[3]*iv;
    float s1 = (h0[0]+h0[1]+h0[2]+h0[3]) + (h1[0]+h1[1]+h1[2]+h1[3])
             + (h2[0]+h2[1]+h2[2]+h2[3]) + (h3[0]+h3[1]+h3[2]+h3[3]);
    float s2 = (h0[0]*h0[0]+h0[1]*h0[1]+h0[2]*h0[2]+h0[3]*h0[3])
             + (h1[0]*h1[0]+h1[1]*h1[1]+h1[2]*h1[2]+h1[3]*h1[3])
             + (h2[0]*h2[0]+h2[1]*h2[1]+h2[2]*h2[2]+h2[3]*h2[3])
             + (h3[0]*h3[0]+h3[1]*h3[1]+h3[2]*h3[2]+h3[3]*h3[3]);
    s1 += __shfl_xor(s1, 1, 64);  s2 += __shfl_xor(s2, 1, 64);
    s1 += __shfl_xor(s1, 2, 64);  s2 += __shfl_xor(s2, 2, 64);
    s1 += __shfl_xor(s1, 4, 64);  s2 += __shfl_xor(s2, 4, 64);
    const float mean = s1*(1.f/128.f);
    const float var  = s2*(1.f/128.f) - mean*mean;
    const float rstd = rsqrtf(var + 1e-5f);
    const float* nb = nw + h*DH + dg*16;
    const f32x4 n0 = *(const f32x4*)(nb+0);
    const f32x4 n1 = *(const f32x4*)(nb+4);
    const f32x4 n2 = *(const f32x4*)(nb+8);
    const f32x4 n3 = *(const f32x4*)(nb+12);
    float* ob = out + (size_t)tq*E_DIM + h*DH + dg*16;
    f32x4 o0v, o1v, o2v, o3v;
    o0v[0]=(h0[0]-mean)*rstd*n0[0]; o0v[1]=(h0[1]-mean)*rstd*n0[1];
    o0v[2]=(h0[2]-mean)*rstd*n0[2]; o0v[3]=(h0[3]-mean)*rstd*n0[3];
    o1v[0]=(h1[0]-mean)*rstd*n1[0]; o1v[1]=(h1[1]-mean)*rstd*n1[1];
    o1v[2]=(h1[2]-mean)*rstd*n1[2]; o1v[3]=(h1[3]-mean)*rstd*n1[3];
    o2v[0]=(h2[0]-mean)*rstd*n2[0]; o2v[1]=(h2[1]-mean)*rstd*n2[1];
    o2v[2]=(h2[2]-mean)*rstd*n2[2]; o2v[3]=(h2[3]-mean)*rstd*n2[3];
    o3v[0]=(h3[0]-mean)*rstd*n3[0]; o3v[1]=(h3[1]-mean)*rstd*n3[1];
    o3v[2]=(h3[2]-mean)*rstd*n3[2]; o3v[3]=(h3[3]-mean)*rstd*n3[3];
    *(f32x4*)(ob+0)  = o0v;
    *(f32x4*)(ob+4)  = o1v;
    *(f32x4*)(ob+8)  = o2v;
    *(f32x4*)(ob+12) = o3v;
  }
}

extern "C" void kernel_launch(void* const* d_in, const int* in_sizes, int n_in,
                              void* d_out, int out_size, void* d_ws, size_t ws_size,
                              hipStream_t stream) {
  const float* q   = (const float*)d_in[0];
  const float* k   = (const float*)d_in[1];
  const float* v   = (const float*)d_in[2];
  const float* igw = (const float*)d_in[3];
  const float* igb = (const float*)d_in[4];
  const float* fgw = (const float*)d_in[5];
  const float* fgb = (const float*)d_in[6];
  const float* nw  = (const float*)d_in[7];
  float* outp = (float*)d_out;

  float* ws  = (float*)d_ws;
  float* ig  = ws;                 // NH*S
  float* lsf = ws + 1*NHEAD*S_LEN;
  float* csb = ws + 2*NHEAD*S_LEN;
  float* Mb  = ws + 3*NHEAD*S_LEN;
  float* mbf = ws + 4*NHEAD*S_LEN;
  ushort* qbb = (ushort*)(ws + 5*NHEAD*S_LEN);          // S*E bf16 (scaled)
  ushort* kbb = qbb + (size_t)S_LEN*E_DIM;              // S*E bf16
  ushort* vtb = kbb + (size_t)S_LEN*E_DIM;              // E*S bf16 (per-head V^T)

  gates_qk<<<S_LEN/4, 256, 0, stream>>>(q, k, v, igw, igb, fgw, fgb,
                                        ig, lsf, qbb, kbb, vtb);
  scan_kernel<<<NHEAD, 256, 0, stream>>>(ig, lsf, csb, Mb, mbf);
  mlstm_mfma6<<<dim3(NHEAD, 64), 256, 0, stream>>>(qbb, kbb, vtb, csb, Mb, mbf, nw, outp);
}